// Round 13
// baseline (1345.154 us; speedup 1.0000x reference)
//
#include <hip/hip_runtime.h>

typedef unsigned int u32;
typedef unsigned short u16;
typedef unsigned long long u64;

typedef __attribute__((ext_vector_type(8))) short short8;     // MFMA A/B frag (8 bf16)
typedef __attribute__((ext_vector_type(4))) float f32x4;      // MFMA C/D frag
typedef __attribute__((ext_vector_type(8))) unsigned short u16x8;
typedef __attribute__((ext_vector_type(4))) unsigned short u16x4;

#define C_DIM 1024
#define B_ROWS 8192
#define N_EMB 8192
#define BN_EPS_C 1e-5f
#define KK 1024   // all GEMMs in this net have K = 1024
#define NKT 32    // K-tiles of 32

// ---------------- bf16 split helpers ---------------------------------------
__device__ __forceinline__ u16 f2bf_rne(float x) {
  u32 b = __float_as_uint(x);
  u32 r = b + 0x7fffu + ((b >> 16) & 1u);
  return (u16)(r >> 16);
}
__device__ __forceinline__ float bf2f(u16 h) {
  return __uint_as_float(((u32)h) << 16);
}

// async global->LDS, 16B/lane; LDS dest = wave-uniform base + lane*16 (HW)
__device__ __forceinline__ void gl2lds(const u16* g, u16* l) {
  __builtin_amdgcn_global_load_lds(
      (const __attribute__((address_space(1))) void*)g,
      (__attribute__((address_space(3))) void*)l, 16, 0, 0);
}

// ---------------- deterministic block reduce (256 threads) ----------------
__device__ __forceinline__ float block_reduce_sum_256(float v) {
#pragma unroll
  for (int off = 32; off > 0; off >>= 1) v += __shfl_xor(v, off, 64);
  __shared__ float sh[4];
  __syncthreads();
  const int lane = threadIdx.x & 63, w = threadIdx.x >> 6;
  if (lane == 0) sh[w] = v;
  __syncthreads();
  return (sh[0] + sh[1]) + (sh[2] + sh[3]);
}

__device__ __forceinline__ u64 shfl_xor_u64(u64 v, int m) {
  int lo = __shfl_xor((int)(u32)v, m, 64);
  int hi = __shfl_xor((int)(u32)(v >> 32), m, 64);
  return ((u64)(u32)hi << 32) | (u32)lo;
}

// ---------------- batched fp32 -> bf16 hi/lo split (4 segments) -------------
__global__ __launch_bounds__(256) void cvt4(
    const float* __restrict__ s0, u16* __restrict__ h0, u16* __restrict__ l0,
    int nb0, const float* __restrict__ s1, u16* __restrict__ h1,
    u16* __restrict__ l1, int nb1, const float* __restrict__ s2,
    u16* __restrict__ h2, u16* __restrict__ l2, int nb2,
    const float* __restrict__ s3, u16* __restrict__ h3, u16* __restrict__ l3) {
  int b = blockIdx.x;
  const float* s;
  u16 *h, *l;
  if (b < nb0) {
    s = s0; h = h0; l = l0;
  } else if (b < nb0 + nb1) {
    b -= nb0; s = s1; h = h1; l = l1;
  } else if (b < nb0 + nb1 + nb2) {
    b -= nb0 + nb1; s = s2; h = h2; l = l2;
  } else {
    b -= nb0 + nb1 + nb2; s = s3; h = h3; l = l3;
  }
  const int i = b * 256 + threadIdx.x;
  const float4 v = ((const float4*)s)[i];
  u16x4 hh, ll;
  hh.x = f2bf_rne(v.x); ll.x = f2bf_rne(v.x - bf2f(hh.x));
  hh.y = f2bf_rne(v.y); ll.y = f2bf_rne(v.y - bf2f(hh.y));
  hh.z = f2bf_rne(v.z); ll.z = f2bf_rne(v.z - bf2f(hh.z));
  hh.w = f2bf_rne(v.w); ll.w = f2bf_rne(v.w - bf2f(hh.w));
  ((u16x4*)h)[i] = hh;
  ((u16x4*)l)[i] = ll;
}

// ---------------- row L2 normalize, optional fp32 + hi/lo + best-init ------
template <int WF32>
__global__ __launch_bounds__(256) void l2norm_ext(const float* __restrict__ in,
                                                  float* __restrict__ outF,
                                                  u16* __restrict__ outH,
                                                  u16* __restrict__ outL,
                                                  float* __restrict__ ssq,
                                                  u64* __restrict__ binit) {
  const int row = blockIdx.x;
  const float4 v = ((const float4*)(in + (size_t)row * C_DIM))[threadIdx.x];
  float ss = v.x * v.x + v.y * v.y + v.z * v.z + v.w * v.w;
  ss = block_reduce_sum_256(ss);
  float nrm = sqrtf(ss);
  nrm = fmaxf(nrm, 1e-12f);
  float4 o;
  o.x = v.x / nrm; o.y = v.y / nrm; o.z = v.z / nrm; o.w = v.w / nrm;
  if (WF32) ((float4*)(outF + (size_t)row * C_DIM))[threadIdx.x] = o;
  u16x4 h, l;
  h.x = f2bf_rne(o.x); l.x = f2bf_rne(o.x - bf2f(h.x));
  h.y = f2bf_rne(o.y); l.y = f2bf_rne(o.y - bf2f(h.y));
  h.z = f2bf_rne(o.z); l.z = f2bf_rne(o.z - bf2f(h.z));
  h.w = f2bf_rne(o.w); l.w = f2bf_rne(o.w - bf2f(h.w));
  ((u16x4*)(outH + (size_t)row * C_DIM))[threadIdx.x] = h;
  ((u16x4*)(outL + (size_t)row * C_DIM))[threadIdx.x] = l;
  float s2 = o.x * o.x + o.y * o.y + o.z * o.z + o.w * o.w;
  s2 = block_reduce_sum_256(s2);
  if (threadIdx.x == 0) {
    ssq[row] = s2;
    if (binit) binit[row] = ~0ull;
  }
}

// ---------------- split-bf16 MFMA NT GEMM ----------------------------------
// C = A@B^T from pre-split hi/lo operands.  Staging: global_load_lds width-16,
// single 32KB buffer, pre-swizzled global source (r10-verified).
// OVERLAP schedule (r13): per K-step, complete ALL ds_reads -> lgkmcnt(0) ->
// barrier -> issue next tile's gl2lds into the now-dead buffer -> MFMAs run
// while loads fly -> vmcnt(0) -> barrier.  Per-acc chain unchanged (hh,hl,
// lh(,ll) per k0) -> BITWISE identical outputs to r12.
// TB=1 (dist): term-batched frags + launch_bounds(256,4) -> VGPR<=64.
// TB=0 (squares): all 16 frags upfront + launch_bounds(256,2).
// TERMS: 3 = hh+hl+lh, 4 = +ll (near-fp32, encoder).
// MODE:  0 = +bias -> fp32 out. 1 = +bias, tanh -> hi/lo out.
//        2 = distance argmin (bias = |e|^2, uses zz/best).
// CS:    1 = emit per-block column sums of out (cs1=sum, cs2=sum of squares).
template <int MODE, int TERMS, int CS, int TB>
__global__ __launch_bounds__(256, (TB ? 4 : 2)) void gemm_bf3(
    const u16* __restrict__ Ahg, const u16* __restrict__ Alg,
    const u16* __restrict__ Bhg, const u16* __restrict__ Blg,
    const float* __restrict__ bias, float* __restrict__ outF,
    u16* __restrict__ outH, u16* __restrict__ outL, float* __restrict__ cs1,
    float* __restrict__ cs2, const float* __restrict__ zz,
    u64* __restrict__ best, int N) {
  // planes: Ah [0,4096), Al [4096,8192), Bh [8192,12288), Bl [12288,16384)
  __shared__ __align__(16) u16 lds[16384];
  __shared__ float csum[CS ? 4 * 64 * 2 : 1];
  const int tid = threadIdx.x;
  const int lane = tid & 63, w = tid >> 6;
  const int wr = w >> 1, wc = w & 1;
  const int m0 = blockIdx.y * 128, n0 = blockIdx.x * 128;

  // staging: wave w covers rows [w*32, w*32+32), 2 issues of 16 rows/array.
  // LDS linear; global source chunk pre-swizzled: c = (lane&3) ^ ((row>>1)&3)
  const int r0l = w * 32 + (lane >> 2);
  const int r1l = r0l + 16;
  const int c0 = (((lane & 3) ^ ((r0l >> 1) & 3)) << 3);
  const int c1 = (((lane & 3) ^ ((r1l >> 1) & 3)) << 3);
  const u16* pAh0 = Ahg + (size_t)(m0 + r0l) * KK + c0;
  const u16* pAh1 = Ahg + (size_t)(m0 + r1l) * KK + c1;
  const u16* pAl0 = Alg + (size_t)(m0 + r0l) * KK + c0;
  const u16* pAl1 = Alg + (size_t)(m0 + r1l) * KK + c1;
  const u16* pBh0 = Bhg + (size_t)(n0 + r0l) * KK + c0;
  const u16* pBh1 = Bhg + (size_t)(n0 + r1l) * KK + c1;
  const u16* pBl0 = Blg + (size_t)(n0 + r0l) * KK + c0;
  const u16* pBl1 = Blg + (size_t)(n0 + r1l) * KK + c1;
  u16* const db = lds + w * 1024;  // wave-uniform LDS dest (32 rows)

  auto STAGE = [&](int ko) {
    gl2lds(pAh0 + ko, db);
    gl2lds(pAh1 + ko, db + 512);
    gl2lds(pAl0 + ko, db + 4096);
    gl2lds(pAl1 + ko, db + 4608);
    gl2lds(pBh0 + ko, db + 8192);
    gl2lds(pBh1 + ko, db + 8704);
    gl2lds(pBl0 + ko, db + 12288);
    gl2lds(pBl1 + ko, db + 12800);
  };

  // fragment-read offsets (u16 units) — identical to r6/r10 (0 conflicts)
  int oa[4], ob[4];
  const int q = lane >> 4;
#pragma unroll
  for (int t = 0; t < 4; ++t) {
    const int ra = wr * 64 + t * 16 + (lane & 15);
    oa[t] = ra * 32 + ((q ^ ((ra >> 1) & 3)) << 3);
    const int rb = wc * 64 + t * 16 + (lane & 15);
    ob[t] = rb * 32 + ((q ^ ((rb >> 1) & 3)) << 3);
  }

  f32x4 acc[4][4];
#pragma unroll
  for (int i = 0; i < 4; ++i)
#pragma unroll
    for (int j = 0; j < 4; ++j) acc[i][j] = (f32x4){0.f, 0.f, 0.f, 0.f};

  STAGE(0);
  asm volatile("s_waitcnt vmcnt(0)" ::: "memory");
  __syncthreads();

  for (int kt = 0; kt < NKT; ++kt) {
    if (TB) {
      // term-batched: peak live frags = 12 (48 VGPRs) -> fits 64-VGPR budget
      short8 fa[4], fb[4], fx[4];
#pragma unroll
      for (int t = 0; t < 4; ++t) {
        fa[t] = *(const short8*)(lds + oa[t]);           // ah
        fb[t] = *(const short8*)(lds + 8192 + ob[t]);    // bh
      }
#pragma unroll
      for (int i = 0; i < 4; ++i)
#pragma unroll
        for (int j = 0; j < 4; ++j)
          acc[i][j] = __builtin_amdgcn_mfma_f32_16x16x32_bf16(
              fa[i], fb[j], acc[i][j], 0, 0, 0);
#pragma unroll
      for (int t = 0; t < 4; ++t)
        fx[t] = *(const short8*)(lds + 12288 + ob[t]);   // bl
#pragma unroll
      for (int i = 0; i < 4; ++i)
#pragma unroll
        for (int j = 0; j < 4; ++j)
          acc[i][j] = __builtin_amdgcn_mfma_f32_16x16x32_bf16(
              fa[i], fx[j], acc[i][j], 0, 0, 0);
#pragma unroll
      for (int t = 0; t < 4; ++t)
        fa[t] = *(const short8*)(lds + 4096 + oa[t]);    // al (ah dead)
      // all LDS reads for this tile are issued; drain + fence + restage
      asm volatile("s_waitcnt lgkmcnt(0)" ::: "memory");
      __builtin_amdgcn_sched_barrier(0);
      __builtin_amdgcn_s_barrier();
      if (kt + 1 < NKT) STAGE((kt + 1) * 32);
#pragma unroll
      for (int i = 0; i < 4; ++i)
#pragma unroll
        for (int j = 0; j < 4; ++j)
          acc[i][j] = __builtin_amdgcn_mfma_f32_16x16x32_bf16(
              fa[i], fb[j], acc[i][j], 0, 0, 0);
      if (TERMS == 4) {
#pragma unroll
        for (int i = 0; i < 4; ++i)
#pragma unroll
          for (int j = 0; j < 4; ++j)
            acc[i][j] = __builtin_amdgcn_mfma_f32_16x16x32_bf16(
                fa[i], fx[j], acc[i][j], 0, 0, 0);
      }
    } else {
      // all 16 frags upfront, then restage, then all MFMAs overlap loads
      short8 ah[4], al[4], bh[4], bl[4];
#pragma unroll
      for (int t = 0; t < 4; ++t) {
        ah[t] = *(const short8*)(lds + oa[t]);
        al[t] = *(const short8*)(lds + 4096 + oa[t]);
        bh[t] = *(const short8*)(lds + 8192 + ob[t]);
        bl[t] = *(const short8*)(lds + 12288 + ob[t]);
      }
      asm volatile("s_waitcnt lgkmcnt(0)" ::: "memory");
      __builtin_amdgcn_sched_barrier(0);
      __builtin_amdgcn_s_barrier();
      if (kt + 1 < NKT) STAGE((kt + 1) * 32);
#pragma unroll
      for (int i = 0; i < 4; ++i)
#pragma unroll
        for (int j = 0; j < 4; ++j) {
          acc[i][j] = __builtin_amdgcn_mfma_f32_16x16x32_bf16(
              ah[i], bh[j], acc[i][j], 0, 0, 0);
          acc[i][j] = __builtin_amdgcn_mfma_f32_16x16x32_bf16(
              ah[i], bl[j], acc[i][j], 0, 0, 0);
          acc[i][j] = __builtin_amdgcn_mfma_f32_16x16x32_bf16(
              al[i], bh[j], acc[i][j], 0, 0, 0);
          if (TERMS == 4)
            acc[i][j] = __builtin_amdgcn_mfma_f32_16x16x32_bf16(
                al[i], bl[j], acc[i][j], 0, 0, 0);
        }
    }
    if (kt + 1 < NKT) {
      asm volatile("s_waitcnt vmcnt(0)" ::: "memory");
      __builtin_amdgcn_sched_barrier(0);
      __builtin_amdgcn_s_barrier();
    }
  }

  // C/D layout: col = lane&15, row = (lane>>4)*4 + v   [m89-verified]
  const int rbase = m0 + wr * 64 + (lane >> 4) * 4;
  const int cbase = n0 + wc * 64 + (lane & 15);

  if (MODE == 2) {
    float sev[4];
#pragma unroll
    for (int j = 0; j < 4; ++j) sev[j] = bias[cbase + j * 16];
#pragma unroll
    for (int i = 0; i < 4; ++i)
#pragma unroll
      for (int v = 0; v < 4; ++v) {
        const int row = rbase + i * 16 + v;
        const float zr = zz[row];
        u64 bkey = ~0ull;
#pragma unroll
        for (int j = 0; j < 4; ++j) {
          const float d = (zr + sev[j]) - 2.0f * acc[i][j][v];
          const u32 fb2 = __float_as_uint(d);
          const u32 k32 = (fb2 & 0x80000000u) ? ~fb2 : (fb2 | 0x80000000u);
          const u64 key = ((u64)k32 << 32) | (u32)(cbase + j * 16);
          bkey = (key < bkey) ? key : bkey;
        }
#pragma unroll
        for (int mm = 1; mm < 16; mm <<= 1) {
          const u64 o = shfl_xor_u64(bkey, mm);
          bkey = (o < bkey) ? o : bkey;
        }
        if ((lane & 15) == 0) atomicMin(best + row, bkey);
      }
  } else {
    float bb[4];
#pragma unroll
    for (int j = 0; j < 4; ++j) bb[j] = bias[cbase + j * 16];
    float s[4] = {0.f, 0.f, 0.f, 0.f}, ss[4] = {0.f, 0.f, 0.f, 0.f};
#pragma unroll
    for (int i = 0; i < 4; ++i)
#pragma unroll
      for (int j = 0; j < 4; ++j)
#pragma unroll
        for (int v = 0; v < 4; ++v) {
          const int row = rbase + i * 16 + v;
          const int col = cbase + j * 16;
          float val = acc[i][j][v] + bb[j];
          if (MODE == 1) {
            val = tanhf(val);
            const u16 h = f2bf_rne(val);
            outH[(size_t)row * N + col] = h;
            outL[(size_t)row * N + col] = f2bf_rne(val - bf2f(h));
          } else {
            outF[(size_t)row * N + col] = val;
            if (CS) {
              s[j] += val;
              ss[j] += val * val;
            }
          }
        }
    if (CS) {
#pragma unroll
      for (int j = 0; j < 4; ++j) {
        s[j] += __shfl_xor(s[j], 16, 64);
        s[j] += __shfl_xor(s[j], 32, 64);
        ss[j] += __shfl_xor(ss[j], 16, 64);
        ss[j] += __shfl_xor(ss[j], 32, 64);
      }
      if (lane < 16) {
#pragma unroll
        for (int j = 0; j < 4; ++j) {
          csum[(w * 64 + j * 16 + lane) * 2 + 0] = s[j];
          csum[(w * 64 + j * 16 + lane) * 2 + 1] = ss[j];
        }
      }
      __syncthreads();
      if (tid < 128) {
        const int col = tid;
        const int wcc = col >> 6, idx = col & 63;
        const float S = csum[(wcc * 64 + idx) * 2 + 0] +
                        csum[((2 + wcc) * 64 + idx) * 2 + 0];
        const float SS = csum[(wcc * 64 + idx) * 2 + 1] +
                         csum[((2 + wcc) * 64 + idx) * 2 + 1];
        cs1[(size_t)blockIdx.y * C_DIM + n0 + col] = S;
        cs2[(size_t)blockIdx.y * C_DIM + n0 + col] = SS;
      }
    }
  }
}

// ---------------- BN finalize: fold 64 per-block partials -------------------
__global__ __launch_bounds__(256) void bn_stats2(const float* __restrict__ cs1,
                                                 const float* __restrict__ cs2,
                                                 const float* __restrict__ g,
                                                 float* __restrict__ mean,
                                                 float* __restrict__ scale) {
  const int c = blockIdx.x * 256 + threadIdx.x;
  float s = 0.f, ss = 0.f;
  for (int i = 0; i < 64; ++i) {
    s += cs1[i * C_DIM + c];
    ss += cs2[i * C_DIM + c];
  }
  const float m = s * (1.0f / 8192.0f);
  const float v = ss * (1.0f / 8192.0f) - m * m;  // biased var
  mean[c] = m;
  scale[c] = g[c] / sqrtf(v + BN_EPS_C);
}

// ---------------- BN apply + ReLU -> hi/lo ---------------------------------
__global__ __launch_bounds__(256) void bn_relu_cvt(
    const float* __restrict__ t, const float* __restrict__ mean,
    const float* __restrict__ scale, const float* __restrict__ be,
    u16* __restrict__ outH, u16* __restrict__ outL) {
  const int i = blockIdx.x * 256 + threadIdx.x;
  const int c4 = i & 255;
  const float4 v = ((const float4*)t)[i];
  const float4 m = ((const float4*)mean)[c4];
  const float4 sc = ((const float4*)scale)[c4];
  const float4 b = ((const float4*)be)[c4];
  float4 r;
  r.x = fmaxf((v.x - m.x) * sc.x + b.x, 0.f);
  r.y = fmaxf((v.y - m.y) * sc.y + b.y, 0.f);
  r.z = fmaxf((v.z - m.z) * sc.z + b.z, 0.f);
  r.w = fmaxf((v.w - m.w) * sc.w + b.w, 0.f);
  u16x4 h, l;
  h.x = f2bf_rne(r.x); l.x = f2bf_rne(r.x - bf2f(h.x));
  h.y = f2bf_rne(r.y); l.y = f2bf_rne(r.y - bf2f(h.y));
  h.z = f2bf_rne(r.z); l.z = f2bf_rne(r.z - bf2f(h.z));
  h.w = f2bf_rne(r.w); l.w = f2bf_rne(r.w - bf2f(h.w));
  ((u16x4*)outH)[i] = h;
  ((u16x4*)outL)[i] = l;
}

// ---------------- VQ gather (hi/lo e) -> zq hi/lo + row loss ----------------
__global__ __launch_bounds__(256) void gather_zq_cvt(
    const float* __restrict__ z, const u16* __restrict__ eh,
    const u16* __restrict__ el, const u64* __restrict__ best,
    u16* __restrict__ zqh, u16* __restrict__ zql, float* __restrict__ rowp) {
  const int row = blockIdx.x;
  const u32 idx = (u32)(best[row] & 0xffffffffu);
  const float4 zv = ((const float4*)(z + (size_t)row * C_DIM))[threadIdx.x];
  const u16x4 evh = ((const u16x4*)(eh + (size_t)idx * C_DIM))[threadIdx.x];
  const u16x4 evl = ((const u16x4*)(el + (size_t)idx * C_DIM))[threadIdx.x];
  float4 ev;
  ev.x = bf2f(evh.x) + bf2f(evl.x);
  ev.y = bf2f(evh.y) + bf2f(evl.y);
  ev.z = bf2f(evh.z) + bf2f(evl.z);
  ev.w = bf2f(evh.w) + bf2f(evl.w);
  float4 d, o;
  d.x = ev.x - zv.x; d.y = ev.y - zv.y; d.z = ev.z - zv.z; d.w = ev.w - zv.w;
  o.x = zv.x + d.x; o.y = zv.y + d.y; o.z = zv.z + d.z; o.w = zv.w + d.w;
  u16x4 h, l;
  h.x = f2bf_rne(o.x); l.x = f2bf_rne(o.x - bf2f(h.x));
  h.y = f2bf_rne(o.y); l.y = f2bf_rne(o.y - bf2f(h.y));
  h.z = f2bf_rne(o.z); l.z = f2bf_rne(o.z - bf2f(h.z));
  h.w = f2bf_rne(o.w); l.w = f2bf_rne(o.w - bf2f(h.w));
  ((u16x4*)(zqh + (size_t)row * C_DIM))[threadIdx.x] = h;
  ((u16x4*)(zql + (size_t)row * C_DIM))[threadIdx.x] = l;
  float ss = d.x * d.x + d.y * d.y + d.z * d.z + d.w * d.w;
  ss = block_reduce_sum_256(ss);
  if (threadIdx.x == 0) rowp[row] = ss;
}

__global__ __launch_bounds__(256) void embloss_fin(const float* __restrict__ rowp,
                                                   float* __restrict__ out) {
  float s = 0.f;
  for (int i = threadIdx.x; i < B_ROWS; i += 256) s += rowp[i];
  s = block_reduce_sum_256(s);
  if (threadIdx.x == 0) out[0] = s * (1.0f / (8192.0f * 1024.0f));
}

// ---------------- launch ----------------------------------------------------
extern "C" void kernel_launch(void* const* d_in, const int* in_sizes, int n_in,
                              void* d_out, int out_size, void* d_ws,
                              size_t ws_size, hipStream_t stream) {
  const float* x = (const float*)d_in[0];
  const float* enc_W = (const float*)d_in[1];
  const float* enc_b = (const float*)d_in[2];
  const float* enc_g = (const float*)d_in[3];
  const float* enc_be = (const float*)d_in[4];
  const float* enc_vW1 = (const float*)d_in[5];
  const float* enc_vb1 = (const float*)d_in[6];
  const float* enc_vW2 = (const float*)d_in[7];
  const float* enc_vb2 = (const float*)d_in[8];
  const float* dec_W = (const float*)d_in[9];
  const float* dec_b = (const float*)d_in[10];
  const float* dec_g = (const float*)d_in[11];
  const float* dec_be = (const float*)d_in[12];
  const float* dec_vW1 = (const float*)d_in[13];
  const float* dec_vb1 = (const float*)d_in[14];
  const float* dec_vW2 = (const float*)d_in[15];
  const float* dec_vb2 = (const float*)d_in[16];
  const float* cb = (const float*)d_in[17];

  const size_t NE = (size_t)B_ROWS * C_DIM;  // 8388608
  const size_t WN = (size_t)C_DIM * C_DIM;   // 1048576
  float* ws = (float*)d_ws;
  // Four NE-float regions, time-shared by liveness (~128.8 MB total):
  float* R1 = ws;        // h fp32 (enc+dec) | z fp32
  float* R2 = R1 + NE;   // x hi/lo | acts ping | zhi/zlo
  float* R3 = R2 + NE;   // acts pong | enc tanh | zq hi/lo
  float* R4 = R3 + NE;   // enc weight arena -> ehi/elo -> dec weight arena
  float* se = R4 + NE;
  float* zz = se + N_EMB;
  u64* best = (u64*)(zz + B_ROWS);
  float* cs1 = (float*)(best + B_ROWS);  // 64*1024
  float* cs2 = cs1 + 64 * C_DIM;         // 64*1024
  float* mean = cs2 + 64 * C_DIM;
  float* scal = mean + C_DIM;
  float* rowp = scal + C_DIM;

  u16* wa = (u16*)R4;
  u16* ehi = (u16*)R4;   // after encoder: codebook hi/lo replace weights
  u16* elo = ehi + NE;
  u16* xh = (u16*)R2;    // x split
  u16* xl = xh + NE;
  u16* aH = (u16*)R2;    // act ping (same region as x: ping-pong below)
  u16* aL = aH + NE;
  u16* bH = (u16*)R3;    // act pong / tanh / zq
  u16* bL = bH + NE;
  u16* zhi = (u16*)R2;   // z hi/lo (acts dead by then)
  u16* zlo = zhi + NE;
  float* zf = R1;        // z fp32 (in-place l2norm of vW2 output)

  float* xrec = (float*)d_out;
  float* loss = xrec + NE;

  const dim3 blk(256);
  const dim3 gemmGrid(C_DIM / 128, B_ROWS / 128);  // (8, 64)
  const dim3 distGrid(N_EMB / 128, B_ROWS / 128);  // (64, 64)
  const dim3 s2Grid(C_DIM / 256);
  const dim3 brGrid(B_ROWS * C_DIM / 1024);

  // ---- one batched split: enc_W(4WN) + vW1 + vW2 + x ----
  cvt4<<<dim3(4096 + 1024 + 1024 + 8192), blk, 0, stream>>>(
      enc_W, wa, wa + 4 * WN, 4096, enc_vW1, wa + 8 * WN, wa + 9 * WN, 1024,
      enc_vW2, wa + 10 * WN, wa + 11 * WN, 1024, x, xh, xl);

  // ---- encoder: 4 x (GEMM+colsum -> stats2 -> bn_relu_cvt) ----
  gemm_bf3<0, 4, 1, 0><<<gemmGrid, blk, 0, stream>>>(
      xh, xl, wa, wa + 4 * WN, enc_b, R1, nullptr, nullptr, cs1, cs2, nullptr,
      nullptr, C_DIM);
  bn_stats2<<<s2Grid, blk, 0, stream>>>(cs1, cs2, enc_g, mean, scal);
  bn_relu_cvt<<<brGrid, blk, 0, stream>>>(R1, mean, scal, enc_be, bH, bL);

  gemm_bf3<0, 4, 1, 0><<<gemmGrid, blk, 0, stream>>>(
      bH, bL, wa + WN, wa + 5 * WN, enc_b + C_DIM, R1, nullptr, nullptr, cs1,
      cs2, nullptr, nullptr, C_DIM);
  bn_stats2<<<s2Grid, blk, 0, stream>>>(cs1, cs2, enc_g + C_DIM, mean, scal);
  bn_relu_cvt<<<brGrid, blk, 0, stream>>>(R1, mean, scal, enc_be + C_DIM, aH,
                                          aL);

  gemm_bf3<0, 4, 1, 0><<<gemmGrid, blk, 0, stream>>>(
      aH, aL, wa + 2 * WN, wa + 6 * WN, enc_b + 2 * C_DIM, R1, nullptr,
      nullptr, cs1, cs2, nullptr, nullptr, C_DIM);
  bn_stats2<<<s2Grid, blk, 0, stream>>>(cs1, cs2, enc_g + 2 * C_DIM, mean,
                                        scal);
  bn_relu_cvt<<<brGrid, blk, 0, stream>>>(R1, mean, scal, enc_be + 2 * C_DIM,
                                          bH, bL);

  gemm_bf3<0, 4, 1, 0><<<gemmGrid, blk, 0, stream>>>(
      bH, bL, wa + 3 * WN, wa + 7 * WN, enc_b + 3 * C_DIM, R1, nullptr,
      nullptr, cs1, cs2, nullptr, nullptr, C_DIM);
  bn_stats2<<<s2Grid, blk, 0, stream>>>(cs1, cs2, enc_g + 3 * C_DIM, mean,
                                        scal);
  bn_relu_cvt<<<brGrid, blk, 0, stream>>>(R1, mean, scal, enc_be + 3 * C_DIM,
                                          aH, aL);

  // enc VQ head: tanh -> bH/bL, then vW2 -> z fp32 (R1)
  gemm_bf3<1, 4, 0, 0><<<gemmGrid, blk, 0, stream>>>(
      aH, aL, wa + 8 * WN, wa + 9 * WN, enc_vb1, nullptr, bH, bL, nullptr,
      nullptr, nullptr, nullptr, C_DIM);
  gemm_bf3<0, 4, 0, 0><<<gemmGrid, blk, 0, stream>>>(
      bH, bL, wa + 10 * WN, wa + 11 * WN, enc_vb2, zf, nullptr, nullptr,
      nullptr, nullptr, nullptr, nullptr, C_DIM);

  // ---- quantizer ----  (enc weights dead -> R4 becomes codebook hi/lo)
  l2norm_ext<0><<<N_EMB, blk, 0, stream>>>(cb, nullptr, ehi, elo, se, nullptr);
  l2norm_ext<1><<<B_ROWS, blk, 0, stream>>>(zf, zf, zhi, zlo, zz, best);
  gemm_bf3<2, 3, 0, 1><<<distGrid, blk, 0, stream>>>(
      zhi, zlo, ehi, elo, se, nullptr, nullptr, nullptr, nullptr, nullptr, zz,
      best, N_EMB);
  gather_zq_cvt<<<B_ROWS, blk, 0, stream>>>(zf, ehi, elo, best, bH, bL, rowp);
  embloss_fin<<<1, blk, 0, stream>>>(rowp, loss);

  // ---- decoder ----  (ehi/elo dead -> R4 becomes decoder weight arena)
  cvt4<<<dim3(4096 + 1024 + 1024), blk, 0, stream>>>(
      dec_W, wa, wa + 4 * WN, 4096, dec_vW1, wa + 8 * WN, wa + 9 * WN, 1024,
      dec_vW2, wa + 10 * WN, wa + 11 * WN, 1024, nullptr, nullptr, nullptr);

  gemm_bf3<0, 3, 1, 0><<<gemmGrid, blk, 0, stream>>>(
      bH, bL, wa, wa + 4 * WN, dec_b, R1, nullptr, nullptr, cs1, cs2, nullptr,
      nullptr, C_DIM);
  bn_stats2<<<s2Grid, blk, 0, stream>>>(cs1, cs2, dec_g, mean, scal);
  bn_relu_cvt<<<brGrid, blk, 0, stream>>>(R1, mean, scal, dec_be, aH, aL);

  gemm_bf3<0, 3, 1, 0><<<gemmGrid, blk, 0, stream>>>(
      aH, aL, wa + WN, wa + 5 * WN, dec_b + C_DIM, R1, nullptr, nullptr, cs1,
      cs2, nullptr, nullptr, C_DIM);
  bn_stats2<<<s2Grid, blk, 0, stream>>>(cs1, cs2, dec_g + C_DIM, mean, scal);
  bn_relu_cvt<<<brGrid, blk, 0, stream>>>(R1, mean, scal, dec_be + C_DIM, bH,
                                          bL);

  gemm_bf3<0, 3, 1, 0><<<gemmGrid, blk, 0, stream>>>(
      bH, bL, wa + 2 * WN, wa + 6 * WN, dec_b + 2 * C_DIM, R1, nullptr,
      nullptr, cs1, cs2, nullptr, nullptr, C_DIM);
  bn_stats2<<<s2Grid, blk, 0, stream>>>(cs1, cs2, dec_g + 2 * C_DIM, mean,
                                        scal);
  bn_relu_cvt<<<brGrid, blk, 0, stream>>>(R1, mean, scal, dec_be + 2 * C_DIM,
                                          aH, aL);

  gemm_bf3<0, 3, 1, 0><<<gemmGrid, blk, 0, stream>>>(
      aH, aL, wa + 3 * WN, wa + 7 * WN, dec_b + 3 * C_DIM, R1, nullptr,
      nullptr, cs1, cs2, nullptr, nullptr, C_DIM);
  bn_stats2<<<s2Grid, blk, 0, stream>>>(cs1, cs2, dec_g + 3 * C_DIM, mean,
                                        scal);
  bn_relu_cvt<<<brGrid, blk, 0, stream>>>(R1, mean, scal, dec_be + 3 * C_DIM,
                                          bH, bL);

  // dec VQ head -> xrec
  gemm_bf3<1, 3, 0, 0><<<gemmGrid, blk, 0, stream>>>(
      bH, bL, wa + 8 * WN, wa + 9 * WN, dec_vb1, nullptr, aH, aL, nullptr,
      nullptr, nullptr, nullptr, C_DIM);
  gemm_bf3<0, 3, 0, 0><<<gemmGrid, blk, 0, stream>>>(
      aH, aL, wa + 10 * WN, wa + 11 * WN, dec_vb2, xrec, nullptr, nullptr,
      nullptr, nullptr, nullptr, nullptr, C_DIM);
}

// Round 14
// 1279.741 us; speedup vs baseline: 1.0511x; 1.0511x over previous
//
#include <hip/hip_runtime.h>

typedef unsigned int u32;
typedef unsigned short u16;
typedef unsigned long long u64;

typedef __attribute__((ext_vector_type(8))) short short8;     // MFMA A/B frag (8 bf16)
typedef __attribute__((ext_vector_type(4))) float f32x4;      // MFMA C/D frag
typedef __attribute__((ext_vector_type(8))) unsigned short u16x8;
typedef __attribute__((ext_vector_type(4))) unsigned short u16x4;

#define C_DIM 1024
#define B_ROWS 8192
#define N_EMB 8192
#define BN_EPS_C 1e-5f
#define KK 1024   // all GEMMs in this net have K = 1024

// ---------------- bf16 split helpers ---------------------------------------
__device__ __forceinline__ u16 f2bf_rne(float x) {
  u32 b = __float_as_uint(x);
  u32 r = b + 0x7fffu + ((b >> 16) & 1u);
  return (u16)(r >> 16);
}
__device__ __forceinline__ float bf2f(u16 h) {
  return __uint_as_float(((u32)h) << 16);
}

// async global->LDS, 16B/lane; LDS dest = wave-uniform base + lane*16 (HW)
__device__ __forceinline__ void gl2lds(const u16* g, u16* l) {
  __builtin_amdgcn_global_load_lds(
      (const __attribute__((address_space(1))) void*)g,
      (__attribute__((address_space(3))) void*)l, 16, 0, 0);
}

// ---------------- deterministic block reduce (256 threads) ----------------
__device__ __forceinline__ float block_reduce_sum_256(float v) {
#pragma unroll
  for (int off = 32; off > 0; off >>= 1) v += __shfl_xor(v, off, 64);
  __shared__ float sh[4];
  __syncthreads();
  const int lane = threadIdx.x & 63, w = threadIdx.x >> 6;
  if (lane == 0) sh[w] = v;
  __syncthreads();
  return (sh[0] + sh[1]) + (sh[2] + sh[3]);
}

__device__ __forceinline__ u64 shfl_xor_u64(u64 v, int m) {
  int lo = __shfl_xor((int)(u32)v, m, 64);
  int hi = __shfl_xor((int)(u32)(v >> 32), m, 64);
  return ((u64)(u32)hi << 32) | (u32)lo;
}

// ---------------- batched fp32 -> bf16 hi/lo split (4 segments) -------------
__global__ __launch_bounds__(256) void cvt4(
    const float* __restrict__ s0, u16* __restrict__ h0, u16* __restrict__ l0,
    int nb0, const float* __restrict__ s1, u16* __restrict__ h1,
    u16* __restrict__ l1, int nb1, const float* __restrict__ s2,
    u16* __restrict__ h2, u16* __restrict__ l2, int nb2,
    const float* __restrict__ s3, u16* __restrict__ h3, u16* __restrict__ l3) {
  int b = blockIdx.x;
  const float* s;
  u16 *h, *l;
  if (b < nb0) {
    s = s0; h = h0; l = l0;
  } else if (b < nb0 + nb1) {
    b -= nb0; s = s1; h = h1; l = l1;
  } else if (b < nb0 + nb1 + nb2) {
    b -= nb0 + nb1; s = s2; h = h2; l = l2;
  } else {
    b -= nb0 + nb1 + nb2; s = s3; h = h3; l = l3;
  }
  const int i = b * 256 + threadIdx.x;
  const float4 v = ((const float4*)s)[i];
  u16x4 hh, ll;
  hh.x = f2bf_rne(v.x); ll.x = f2bf_rne(v.x - bf2f(hh.x));
  hh.y = f2bf_rne(v.y); ll.y = f2bf_rne(v.y - bf2f(hh.y));
  hh.z = f2bf_rne(v.z); ll.z = f2bf_rne(v.z - bf2f(hh.z));
  hh.w = f2bf_rne(v.w); ll.w = f2bf_rne(v.w - bf2f(hh.w));
  ((u16x4*)h)[i] = hh;
  ((u16x4*)l)[i] = ll;
}

// ---------------- row L2 normalize, optional fp32 + hi/lo + best-init ------
template <int WF32>
__global__ __launch_bounds__(256) void l2norm_ext(const float* __restrict__ in,
                                                  float* __restrict__ outF,
                                                  u16* __restrict__ outH,
                                                  u16* __restrict__ outL,
                                                  float* __restrict__ ssq,
                                                  u64* __restrict__ binit) {
  const int row = blockIdx.x;
  const float4 v = ((const float4*)(in + (size_t)row * C_DIM))[threadIdx.x];
  float ss = v.x * v.x + v.y * v.y + v.z * v.z + v.w * v.w;
  ss = block_reduce_sum_256(ss);
  float nrm = sqrtf(ss);
  nrm = fmaxf(nrm, 1e-12f);
  float4 o;
  o.x = v.x / nrm; o.y = v.y / nrm; o.z = v.z / nrm; o.w = v.w / nrm;
  if (WF32) ((float4*)(outF + (size_t)row * C_DIM))[threadIdx.x] = o;
  u16x4 h, l;
  h.x = f2bf_rne(o.x); l.x = f2bf_rne(o.x - bf2f(h.x));
  h.y = f2bf_rne(o.y); l.y = f2bf_rne(o.y - bf2f(h.y));
  h.z = f2bf_rne(o.z); l.z = f2bf_rne(o.z - bf2f(h.z));
  h.w = f2bf_rne(o.w); l.w = f2bf_rne(o.w - bf2f(h.w));
  ((u16x4*)(outH + (size_t)row * C_DIM))[threadIdx.x] = h;
  ((u16x4*)(outL + (size_t)row * C_DIM))[threadIdx.x] = l;
  float s2 = o.x * o.x + o.y * o.y + o.z * o.z + o.w * o.w;
  s2 = block_reduce_sum_256(s2);
  if (threadIdx.x == 0) {
    ssq[row] = s2;
    if (binit) binit[row] = ~0ull;
  }
}

// ---------------- split-bf16 MFMA NT GEMM (r12 core + XCD tile swizzle) -----
// C = A@B^T from pre-split hi/lo operands.  Staging: global_load_lds width-16,
// single 32KB buffer, pre-swizzled global source (r10-verified).
// XCD tile swizzle (bijective; grids 512/4096 are %8==0): consecutive tiles
// that share a z-panel land on the SAME XCD L2 -> panel fetched once per XCD.
// Pure block->tile remap: outputs bitwise identical to r12.
// TB=1 (dist): term-batched frags + launch_bounds(256,4) -> VGPR<=64.
// TB=0 (squares): all 16 frags upfront + launch_bounds(256,2).
// TERMS: 3 = hh+hl+lh, 4 = +ll (near-fp32, encoder).
// MODE:  0 = +bias -> fp32 out. 1 = +bias, tanh -> hi/lo out.
//        2 = distance argmin (bias = |e|^2, uses zz/best).
// CS:    1 = emit per-block column sums of out (cs1=sum, cs2=sum of squares).
template <int MODE, int TERMS, int CS, int TB>
__global__ __launch_bounds__(256, (TB ? 4 : 2)) void gemm_bf3(
    const u16* __restrict__ Ahg, const u16* __restrict__ Alg,
    const u16* __restrict__ Bhg, const u16* __restrict__ Blg,
    const float* __restrict__ bias, float* __restrict__ outF,
    u16* __restrict__ outH, u16* __restrict__ outL, float* __restrict__ cs1,
    float* __restrict__ cs2, const float* __restrict__ zz,
    u64* __restrict__ best, int N) {
  // planes: Ah [0,4096), Al [4096,8192), Bh [8192,12288), Bl [12288,16384)
  __shared__ __align__(16) u16 lds[16384];
  __shared__ float csum[CS ? 4 * 64 * 2 : 1];
  const int tid = threadIdx.x;
  const int lane = tid & 63, w = tid >> 6;
  const int wr = w >> 1, wc = w & 1;

  // XCD-aware bijective tile remap: bid' = (bid&7)*(nb/8) + (bid>>3)
  const int gx = gridDim.x;
  const int nb = gx * gridDim.y;
  int bid = blockIdx.y * gx + blockIdx.x;
  bid = (bid & 7) * (nb >> 3) + (bid >> 3);
  const int bx = bid % gx, by = bid / gx;
  const int m0 = by * 128, n0 = bx * 128;

  // staging: wave w covers rows [w*32, w*32+32), 2 issues of 16 rows/array.
  // LDS linear; global source chunk pre-swizzled: c = (lane&3) ^ ((row>>1)&3)
  const int r0l = w * 32 + (lane >> 2);
  const int r1l = r0l + 16;
  const int c0 = (((lane & 3) ^ ((r0l >> 1) & 3)) << 3);
  const int c1 = (((lane & 3) ^ ((r1l >> 1) & 3)) << 3);
  const u16* pAh0 = Ahg + (size_t)(m0 + r0l) * KK + c0;
  const u16* pAh1 = Ahg + (size_t)(m0 + r1l) * KK + c1;
  const u16* pAl0 = Alg + (size_t)(m0 + r0l) * KK + c0;
  const u16* pAl1 = Alg + (size_t)(m0 + r1l) * KK + c1;
  const u16* pBh0 = Bhg + (size_t)(n0 + r0l) * KK + c0;
  const u16* pBh1 = Bhg + (size_t)(n0 + r1l) * KK + c1;
  const u16* pBl0 = Blg + (size_t)(n0 + r0l) * KK + c0;
  const u16* pBl1 = Blg + (size_t)(n0 + r1l) * KK + c1;
  u16* const db = lds + w * 1024;  // wave-uniform LDS dest (32 rows)

  // fragment-read offsets (u16 units) — identical to r6/r10 (0 conflicts)
  int oa[4], ob[4];
  const int q = lane >> 4;
#pragma unroll
  for (int t = 0; t < 4; ++t) {
    const int ra = wr * 64 + t * 16 + (lane & 15);
    oa[t] = ra * 32 + ((q ^ ((ra >> 1) & 3)) << 3);
    const int rb = wc * 64 + t * 16 + (lane & 15);
    ob[t] = rb * 32 + ((q ^ ((rb >> 1) & 3)) << 3);
  }

  f32x4 acc[4][4];
#pragma unroll
  for (int i = 0; i < 4; ++i)
#pragma unroll
    for (int j = 0; j < 4; ++j) acc[i][j] = (f32x4){0.f, 0.f, 0.f, 0.f};

  for (int k0 = 0; k0 < KK; k0 += 32) {
    __syncthreads();  // all waves done reading previous tile
    gl2lds(pAh0 + k0, db);
    gl2lds(pAh1 + k0, db + 512);
    gl2lds(pAl0 + k0, db + 4096);
    gl2lds(pAl1 + k0, db + 4608);
    gl2lds(pBh0 + k0, db + 8192);
    gl2lds(pBh1 + k0, db + 8704);
    gl2lds(pBl0 + k0, db + 12288);
    gl2lds(pBl1 + k0, db + 12800);
    asm volatile("s_waitcnt vmcnt(0)" ::: "memory");
    __syncthreads();  // every wave's tile landed

    if (TB) {
      // term-batched: peak live frags = 12 (48 VGPRs) -> fits 64-VGPR budget
      short8 fa[4], fb[4], fx[4];
#pragma unroll
      for (int t = 0; t < 4; ++t) {
        fa[t] = *(const short8*)(lds + oa[t]);           // ah
        fb[t] = *(const short8*)(lds + 8192 + ob[t]);    // bh
      }
#pragma unroll
      for (int i = 0; i < 4; ++i)
#pragma unroll
        for (int j = 0; j < 4; ++j)
          acc[i][j] = __builtin_amdgcn_mfma_f32_16x16x32_bf16(
              fa[i], fb[j], acc[i][j], 0, 0, 0);
#pragma unroll
      for (int t = 0; t < 4; ++t)
        fx[t] = *(const short8*)(lds + 12288 + ob[t]);   // bl
#pragma unroll
      for (int i = 0; i < 4; ++i)
#pragma unroll
        for (int j = 0; j < 4; ++j)
          acc[i][j] = __builtin_amdgcn_mfma_f32_16x16x32_bf16(
              fa[i], fx[j], acc[i][j], 0, 0, 0);
#pragma unroll
      for (int t = 0; t < 4; ++t)
        fa[t] = *(const short8*)(lds + 4096 + oa[t]);    // al (ah dead)
#pragma unroll
      for (int i = 0; i < 4; ++i)
#pragma unroll
        for (int j = 0; j < 4; ++j)
          acc[i][j] = __builtin_amdgcn_mfma_f32_16x16x32_bf16(
              fa[i], fb[j], acc[i][j], 0, 0, 0);
      if (TERMS == 4) {
#pragma unroll
        for (int i = 0; i < 4; ++i)
#pragma unroll
          for (int j = 0; j < 4; ++j)
            acc[i][j] = __builtin_amdgcn_mfma_f32_16x16x32_bf16(
                fa[i], fx[j], acc[i][j], 0, 0, 0);
      }
    } else {
      // r10 body: all 16 frags upfront, per-acc hh,hl,lh(,ll)
      short8 ah[4], al[4], bh[4], bl[4];
#pragma unroll
      for (int t = 0; t < 4; ++t) {
        ah[t] = *(const short8*)(lds + oa[t]);
        al[t] = *(const short8*)(lds + 4096 + oa[t]);
        bh[t] = *(const short8*)(lds + 8192 + ob[t]);
        bl[t] = *(const short8*)(lds + 12288 + ob[t]);
      }
#pragma unroll
      for (int i = 0; i < 4; ++i)
#pragma unroll
        for (int j = 0; j < 4; ++j) {
          acc[i][j] = __builtin_amdgcn_mfma_f32_16x16x32_bf16(
              ah[i], bh[j], acc[i][j], 0, 0, 0);
          acc[i][j] = __builtin_amdgcn_mfma_f32_16x16x32_bf16(
              ah[i], bl[j], acc[i][j], 0, 0, 0);
          acc[i][j] = __builtin_amdgcn_mfma_f32_16x16x32_bf16(
              al[i], bh[j], acc[i][j], 0, 0, 0);
          if (TERMS == 4)
            acc[i][j] = __builtin_amdgcn_mfma_f32_16x16x32_bf16(
                al[i], bl[j], acc[i][j], 0, 0, 0);
        }
    }
  }

  // C/D layout: col = lane&15, row = (lane>>4)*4 + v   [m89-verified]
  const int rbase = m0 + wr * 64 + (lane >> 4) * 4;
  const int cbase = n0 + wc * 64 + (lane & 15);

  if (MODE == 2) {
    float sev[4];
#pragma unroll
    for (int j = 0; j < 4; ++j) sev[j] = bias[cbase + j * 16];
#pragma unroll
    for (int i = 0; i < 4; ++i)
#pragma unroll
      for (int v = 0; v < 4; ++v) {
        const int row = rbase + i * 16 + v;
        const float zr = zz[row];
        u64 bkey = ~0ull;
#pragma unroll
        for (int j = 0; j < 4; ++j) {
          const float d = (zr + sev[j]) - 2.0f * acc[i][j][v];
          const u32 fb2 = __float_as_uint(d);
          const u32 k32 = (fb2 & 0x80000000u) ? ~fb2 : (fb2 | 0x80000000u);
          const u64 key = ((u64)k32 << 32) | (u32)(cbase + j * 16);
          bkey = (key < bkey) ? key : bkey;
        }
#pragma unroll
        for (int mm = 1; mm < 16; mm <<= 1) {
          const u64 o = shfl_xor_u64(bkey, mm);
          bkey = (o < bkey) ? o : bkey;
        }
        if ((lane & 15) == 0) atomicMin(best + row, bkey);
      }
  } else {
    float bb[4];
#pragma unroll
    for (int j = 0; j < 4; ++j) bb[j] = bias[cbase + j * 16];
    float s[4] = {0.f, 0.f, 0.f, 0.f}, ss[4] = {0.f, 0.f, 0.f, 0.f};
#pragma unroll
    for (int i = 0; i < 4; ++i)
#pragma unroll
      for (int j = 0; j < 4; ++j)
#pragma unroll
        for (int v = 0; v < 4; ++v) {
          const int row = rbase + i * 16 + v;
          const int col = cbase + j * 16;
          float val = acc[i][j][v] + bb[j];
          if (MODE == 1) {
            val = tanhf(val);
            const u16 h = f2bf_rne(val);
            outH[(size_t)row * N + col] = h;
            outL[(size_t)row * N + col] = f2bf_rne(val - bf2f(h));
          } else {
            outF[(size_t)row * N + col] = val;
            if (CS) {
              s[j] += val;
              ss[j] += val * val;
            }
          }
        }
    if (CS) {
#pragma unroll
      for (int j = 0; j < 4; ++j) {
        s[j] += __shfl_xor(s[j], 16, 64);
        s[j] += __shfl_xor(s[j], 32, 64);
        ss[j] += __shfl_xor(ss[j], 16, 64);
        ss[j] += __shfl_xor(ss[j], 32, 64);
      }
      if (lane < 16) {
#pragma unroll
        for (int j = 0; j < 4; ++j) {
          csum[(w * 64 + j * 16 + lane) * 2 + 0] = s[j];
          csum[(w * 64 + j * 16 + lane) * 2 + 1] = ss[j];
        }
      }
      __syncthreads();
      if (tid < 128) {
        const int col = tid;
        const int wcc = col >> 6, idx = col & 63;
        const float S = csum[(wcc * 64 + idx) * 2 + 0] +
                        csum[((2 + wcc) * 64 + idx) * 2 + 0];
        const float SS = csum[(wcc * 64 + idx) * 2 + 1] +
                         csum[((2 + wcc) * 64 + idx) * 2 + 1];
        cs1[(size_t)by * C_DIM + n0 + col] = S;
        cs2[(size_t)by * C_DIM + n0 + col] = SS;
      }
    }
  }
}

// ---------------- BN finalize: fold 64 per-block partials -------------------
__global__ __launch_bounds__(256) void bn_stats2(const float* __restrict__ cs1,
                                                 const float* __restrict__ cs2,
                                                 const float* __restrict__ g,
                                                 float* __restrict__ mean,
                                                 float* __restrict__ scale) {
  const int c = blockIdx.x * 256 + threadIdx.x;
  float s = 0.f, ss = 0.f;
  for (int i = 0; i < 64; ++i) {
    s += cs1[i * C_DIM + c];
    ss += cs2[i * C_DIM + c];
  }
  const float m = s * (1.0f / 8192.0f);
  const float v = ss * (1.0f / 8192.0f) - m * m;  // biased var
  mean[c] = m;
  scale[c] = g[c] / sqrtf(v + BN_EPS_C);
}

// ---------------- BN apply + ReLU -> hi/lo ---------------------------------
__global__ __launch_bounds__(256) void bn_relu_cvt(
    const float* __restrict__ t, const float* __restrict__ mean,
    const float* __restrict__ scale, const float* __restrict__ be,
    u16* __restrict__ outH, u16* __restrict__ outL) {
  const int i = blockIdx.x * 256 + threadIdx.x;
  const int c4 = i & 255;
  const float4 v = ((const float4*)t)[i];
  const float4 m = ((const float4*)mean)[c4];
  const float4 sc = ((const float4*)scale)[c4];
  const float4 b = ((const float4*)be)[c4];
  float4 r;
  r.x = fmaxf((v.x - m.x) * sc.x + b.x, 0.f);
  r.y = fmaxf((v.y - m.y) * sc.y + b.y, 0.f);
  r.z = fmaxf((v.z - m.z) * sc.z + b.z, 0.f);
  r.w = fmaxf((v.w - m.w) * sc.w + b.w, 0.f);
  u16x4 h, l;
  h.x = f2bf_rne(r.x); l.x = f2bf_rne(r.x - bf2f(h.x));
  h.y = f2bf_rne(r.y); l.y = f2bf_rne(r.y - bf2f(h.y));
  h.z = f2bf_rne(r.z); l.z = f2bf_rne(r.z - bf2f(h.z));
  h.w = f2bf_rne(r.w); l.w = f2bf_rne(r.w - bf2f(h.w));
  ((u16x4*)outH)[i] = h;
  ((u16x4*)outL)[i] = l;
}

// ---------------- VQ gather (hi/lo e) -> zq hi/lo + row loss ----------------
__global__ __launch_bounds__(256) void gather_zq_cvt(
    const float* __restrict__ z, const u16* __restrict__ eh,
    const u16* __restrict__ el, const u64* __restrict__ best,
    u16* __restrict__ zqh, u16* __restrict__ zql, float* __restrict__ rowp) {
  const int row = blockIdx.x;
  const u32 idx = (u32)(best[row] & 0xffffffffu);
  const float4 zv = ((const float4*)(z + (size_t)row * C_DIM))[threadIdx.x];
  const u16x4 evh = ((const u16x4*)(eh + (size_t)idx * C_DIM))[threadIdx.x];
  const u16x4 evl = ((const u16x4*)(el + (size_t)idx * C_DIM))[threadIdx.x];
  float4 ev;
  ev.x = bf2f(evh.x) + bf2f(evl.x);
  ev.y = bf2f(evh.y) + bf2f(evl.y);
  ev.z = bf2f(evh.z) + bf2f(evl.z);
  ev.w = bf2f(evh.w) + bf2f(evl.w);
  float4 d, o;
  d.x = ev.x - zv.x; d.y = ev.y - zv.y; d.z = ev.z - zv.z; d.w = ev.w - zv.w;
  o.x = zv.x + d.x; o.y = zv.y + d.y; o.z = zv.z + d.z; o.w = zv.w + d.w;
  u16x4 h, l;
  h.x = f2bf_rne(o.x); l.x = f2bf_rne(o.x - bf2f(h.x));
  h.y = f2bf_rne(o.y); l.y = f2bf_rne(o.y - bf2f(h.y));
  h.z = f2bf_rne(o.z); l.z = f2bf_rne(o.z - bf2f(h.z));
  h.w = f2bf_rne(o.w); l.w = f2bf_rne(o.w - bf2f(h.w));
  ((u16x4*)(zqh + (size_t)row * C_DIM))[threadIdx.x] = h;
  ((u16x4*)(zql + (size_t)row * C_DIM))[threadIdx.x] = l;
  float ss = d.x * d.x + d.y * d.y + d.z * d.z + d.w * d.w;
  ss = block_reduce_sum_256(ss);
  if (threadIdx.x == 0) rowp[row] = ss;
}

__global__ __launch_bounds__(256) void embloss_fin(const float* __restrict__ rowp,
                                                   float* __restrict__ out) {
  float s = 0.f;
  for (int i = threadIdx.x; i < B_ROWS; i += 256) s += rowp[i];
  s = block_reduce_sum_256(s);
  if (threadIdx.x == 0) out[0] = s * (1.0f / (8192.0f * 1024.0f));
}

// ---------------- launch ----------------------------------------------------
extern "C" void kernel_launch(void* const* d_in, const int* in_sizes, int n_in,
                              void* d_out, int out_size, void* d_ws,
                              size_t ws_size, hipStream_t stream) {
  const float* x = (const float*)d_in[0];
  const float* enc_W = (const float*)d_in[1];
  const float* enc_b = (const float*)d_in[2];
  const float* enc_g = (const float*)d_in[3];
  const float* enc_be = (const float*)d_in[4];
  const float* enc_vW1 = (const float*)d_in[5];
  const float* enc_vb1 = (const float*)d_in[6];
  const float* enc_vW2 = (const float*)d_in[7];
  const float* enc_vb2 = (const float*)d_in[8];
  const float* dec_W = (const float*)d_in[9];
  const float* dec_b = (const float*)d_in[10];
  const float* dec_g = (const float*)d_in[11];
  const float* dec_be = (const float*)d_in[12];
  const float* dec_vW1 = (const float*)d_in[13];
  const float* dec_vb1 = (const float*)d_in[14];
  const float* dec_vW2 = (const float*)d_in[15];
  const float* dec_vb2 = (const float*)d_in[16];
  const float* cb = (const float*)d_in[17];

  const size_t NE = (size_t)B_ROWS * C_DIM;  // 8388608
  const size_t WN = (size_t)C_DIM * C_DIM;   // 1048576
  float* ws = (float*)d_ws;
  // Four NE-float regions, time-shared by liveness (~128.8 MB total):
  float* R1 = ws;        // h fp32 (enc+dec) | z fp32
  float* R2 = R1 + NE;   // x hi/lo | acts ping | zhi/zlo
  float* R3 = R2 + NE;   // acts pong | enc tanh | zq hi/lo
  float* R4 = R3 + NE;   // enc weight arena -> ehi/elo -> dec weight arena
  float* se = R4 + NE;
  float* zz = se + N_EMB;
  u64* best = (u64*)(zz + B_ROWS);
  float* cs1 = (float*)(best + B_ROWS);  // 64*1024
  float* cs2 = cs1 + 64 * C_DIM;         // 64*1024
  float* mean = cs2 + 64 * C_DIM;
  float* scal = mean + C_DIM;
  float* rowp = scal + C_DIM;

  u16* wa = (u16*)R4;
  u16* ehi = (u16*)R4;   // after encoder: codebook hi/lo replace weights
  u16* elo = ehi + NE;
  u16* xh = (u16*)R2;    // x split
  u16* xl = xh + NE;
  u16* aH = (u16*)R2;    // act ping (same region as x: ping-pong below)
  u16* aL = aH + NE;
  u16* bH = (u16*)R3;    // act pong / tanh / zq
  u16* bL = bH + NE;
  u16* zhi = (u16*)R2;   // z hi/lo (acts dead by then)
  u16* zlo = zhi + NE;
  float* zf = R1;        // z fp32 (in-place l2norm of vW2 output)

  float* xrec = (float*)d_out;
  float* loss = xrec + NE;

  const dim3 blk(256);
  const dim3 gemmGrid(C_DIM / 128, B_ROWS / 128);  // (8, 64)
  const dim3 distGrid(N_EMB / 128, B_ROWS / 128);  // (64, 64)
  const dim3 s2Grid(C_DIM / 256);
  const dim3 brGrid(B_ROWS * C_DIM / 1024);

  // ---- one batched split: enc_W(4WN) + vW1 + vW2 + x ----
  cvt4<<<dim3(4096 + 1024 + 1024 + 8192), blk, 0, stream>>>(
      enc_W, wa, wa + 4 * WN, 4096, enc_vW1, wa + 8 * WN, wa + 9 * WN, 1024,
      enc_vW2, wa + 10 * WN, wa + 11 * WN, 1024, x, xh, xl);

  // ---- encoder: 4 x (GEMM+colsum -> stats2 -> bn_relu_cvt) ----
  gemm_bf3<0, 4, 1, 0><<<gemmGrid, blk, 0, stream>>>(
      xh, xl, wa, wa + 4 * WN, enc_b, R1, nullptr, nullptr, cs1, cs2, nullptr,
      nullptr, C_DIM);
  bn_stats2<<<s2Grid, blk, 0, stream>>>(cs1, cs2, enc_g, mean, scal);
  bn_relu_cvt<<<brGrid, blk, 0, stream>>>(R1, mean, scal, enc_be, bH, bL);

  gemm_bf3<0, 4, 1, 0><<<gemmGrid, blk, 0, stream>>>(
      bH, bL, wa + WN, wa + 5 * WN, enc_b + C_DIM, R1, nullptr, nullptr, cs1,
      cs2, nullptr, nullptr, C_DIM);
  bn_stats2<<<s2Grid, blk, 0, stream>>>(cs1, cs2, enc_g + C_DIM, mean, scal);
  bn_relu_cvt<<<brGrid, blk, 0, stream>>>(R1, mean, scal, enc_be + C_DIM, aH,
                                          aL);

  gemm_bf3<0, 4, 1, 0><<<gemmGrid, blk, 0, stream>>>(
      aH, aL, wa + 2 * WN, wa + 6 * WN, enc_b + 2 * C_DIM, R1, nullptr,
      nullptr, cs1, cs2, nullptr, nullptr, C_DIM);
  bn_stats2<<<s2Grid, blk, 0, stream>>>(cs1, cs2, enc_g + 2 * C_DIM, mean,
                                        scal);
  bn_relu_cvt<<<brGrid, blk, 0, stream>>>(R1, mean, scal, enc_be + 2 * C_DIM,
                                          bH, bL);

  gemm_bf3<0, 4, 1, 0><<<gemmGrid, blk, 0, stream>>>(
      bH, bL, wa + 3 * WN, wa + 7 * WN, enc_b + 3 * C_DIM, R1, nullptr,
      nullptr, cs1, cs2, nullptr, nullptr, C_DIM);
  bn_stats2<<<s2Grid, blk, 0, stream>>>(cs1, cs2, enc_g + 3 * C_DIM, mean,
                                        scal);
  bn_relu_cvt<<<brGrid, blk, 0, stream>>>(R1, mean, scal, enc_be + 3 * C_DIM,
                                          aH, aL);

  // enc VQ head: tanh -> bH/bL, then vW2 -> z fp32 (R1)
  gemm_bf3<1, 4, 0, 0><<<gemmGrid, blk, 0, stream>>>(
      aH, aL, wa + 8 * WN, wa + 9 * WN, enc_vb1, nullptr, bH, bL, nullptr,
      nullptr, nullptr, nullptr, C_DIM);
  gemm_bf3<0, 4, 0, 0><<<gemmGrid, blk, 0, stream>>>(
      bH, bL, wa + 10 * WN, wa + 11 * WN, enc_vb2, zf, nullptr, nullptr,
      nullptr, nullptr, nullptr, nullptr, C_DIM);

  // ---- quantizer ----  (enc weights dead -> R4 becomes codebook hi/lo)
  l2norm_ext<0><<<N_EMB, blk, 0, stream>>>(cb, nullptr, ehi, elo, se, nullptr);
  l2norm_ext<1><<<B_ROWS, blk, 0, stream>>>(zf, zf, zhi, zlo, zz, best);
  gemm_bf3<2, 3, 0, 1><<<distGrid, blk, 0, stream>>>(
      zhi, zlo, ehi, elo, se, nullptr, nullptr, nullptr, nullptr, nullptr, zz,
      best, N_EMB);
  gather_zq_cvt<<<B_ROWS, blk, 0, stream>>>(zf, ehi, elo, best, bH, bL, rowp);
  embloss_fin<<<1, blk, 0, stream>>>(rowp, loss);

  // ---- decoder ----  (ehi/elo dead -> R4 becomes decoder weight arena)
  cvt4<<<dim3(4096 + 1024 + 1024), blk, 0, stream>>>(
      dec_W, wa, wa + 4 * WN, 4096, dec_vW1, wa + 8 * WN, wa + 9 * WN, 1024,
      dec_vW2, wa + 10 * WN, wa + 11 * WN, 1024, nullptr, nullptr, nullptr);

  gemm_bf3<0, 3, 1, 0><<<gemmGrid, blk, 0, stream>>>(
      bH, bL, wa, wa + 4 * WN, dec_b, R1, nullptr, nullptr, cs1, cs2, nullptr,
      nullptr, C_DIM);
  bn_stats2<<<s2Grid, blk, 0, stream>>>(cs1, cs2, dec_g, mean, scal);
  bn_relu_cvt<<<brGrid, blk, 0, stream>>>(R1, mean, scal, dec_be, aH, aL);

  gemm_bf3<0, 3, 1, 0><<<gemmGrid, blk, 0, stream>>>(
      aH, aL, wa + WN, wa + 5 * WN, dec_b + C_DIM, R1, nullptr, nullptr, cs1,
      cs2, nullptr, nullptr, C_DIM);
  bn_stats2<<<s2Grid, blk, 0, stream>>>(cs1, cs2, dec_g + C_DIM, mean, scal);
  bn_relu_cvt<<<brGrid, blk, 0, stream>>>(R1, mean, scal, dec_be + C_DIM, bH,
                                          bL);

  gemm_bf3<0, 3, 1, 0><<<gemmGrid, blk, 0, stream>>>(
      bH, bL, wa + 2 * WN, wa + 6 * WN, dec_b + 2 * C_DIM, R1, nullptr,
      nullptr, cs1, cs2, nullptr, nullptr, C_DIM);
  bn_stats2<<<s2Grid, blk, 0, stream>>>(cs1, cs2, dec_g + 2 * C_DIM, mean,
                                        scal);
  bn_relu_cvt<<<brGrid, blk, 0, stream>>>(R1, mean, scal, dec_be + 2 * C_DIM,
                                          aH, aL);

  gemm_bf3<0, 3, 1, 0><<<gemmGrid, blk, 0, stream>>>(
      aH, aL, wa + 3 * WN, wa + 7 * WN, dec_b + 3 * C_DIM, R1, nullptr,
      nullptr, cs1, cs2, nullptr, nullptr, C_DIM);
  bn_stats2<<<s2Grid, blk, 0, stream>>>(cs1, cs2, dec_g + 3 * C_DIM, mean,
                                        scal);
  bn_relu_cvt<<<brGrid, blk, 0, stream>>>(R1, mean, scal, dec_be + 3 * C_DIM,
                                          bH, bL);

  // dec VQ head -> xrec
  gemm_bf3<1, 3, 0, 0><<<gemmGrid, blk, 0, stream>>>(
      bH, bL, wa + 8 * WN, wa + 9 * WN, dec_vb1, nullptr, aH, aL, nullptr,
      nullptr, nullptr, nullptr, C_DIM);
  gemm_bf3<0, 3, 0, 0><<<gemmGrid, blk, 0, stream>>>(
      aH, aL, wa + 10 * WN, wa + 11 * WN, dec_vb2, xrec, nullptr, nullptr,
      nullptr, nullptr, nullptr, nullptr, C_DIM);
}

// Round 15
// 1204.830 us; speedup vs baseline: 1.1165x; 1.0622x over previous
//
#include <hip/hip_runtime.h>

typedef unsigned int u32;
typedef unsigned short u16;
typedef unsigned long long u64;

typedef __attribute__((ext_vector_type(8))) short short8;     // MFMA A/B frag (8 bf16)
typedef __attribute__((ext_vector_type(4))) float f32x4;      // MFMA C/D frag
typedef __attribute__((ext_vector_type(8))) unsigned short u16x8;
typedef __attribute__((ext_vector_type(4))) unsigned short u16x4;

#define C_DIM 1024
#define B_ROWS 8192
#define N_EMB 8192
#define BN_EPS_C 1e-5f
#define KK 1024   // all GEMMs in this net have K = 1024

// ---------------- bf16 split helpers ---------------------------------------
__device__ __forceinline__ u16 f2bf_rne(float x) {
  u32 b = __float_as_uint(x);
  u32 r = b + 0x7fffu + ((b >> 16) & 1u);
  return (u16)(r >> 16);
}
__device__ __forceinline__ float bf2f(u16 h) {
  return __uint_as_float(((u32)h) << 16);
}

// async global->LDS, 16B/lane; LDS dest = wave-uniform base + lane*16 (HW)
__device__ __forceinline__ void gl2lds(const u16* g, u16* l) {
  __builtin_amdgcn_global_load_lds(
      (const __attribute__((address_space(1))) void*)g,
      (__attribute__((address_space(3))) void*)l, 16, 0, 0);
}

// ---------------- deterministic block reduce (256 threads) ----------------
__device__ __forceinline__ float block_reduce_sum_256(float v) {
#pragma unroll
  for (int off = 32; off > 0; off >>= 1) v += __shfl_xor(v, off, 64);
  __shared__ float sh[4];
  __syncthreads();
  const int lane = threadIdx.x & 63, w = threadIdx.x >> 6;
  if (lane == 0) sh[w] = v;
  __syncthreads();
  return (sh[0] + sh[1]) + (sh[2] + sh[3]);
}

__device__ __forceinline__ u64 shfl_xor_u64(u64 v, int m) {
  int lo = __shfl_xor((int)(u32)v, m, 64);
  int hi = __shfl_xor((int)(u32)(v >> 32), m, 64);
  return ((u64)(u32)hi << 32) | (u32)lo;
}

// ---------------- batched fp32 -> bf16 hi/lo split (4 segments) -------------
__global__ __launch_bounds__(256) void cvt4(
    const float* __restrict__ s0, u16* __restrict__ h0, u16* __restrict__ l0,
    int nb0, const float* __restrict__ s1, u16* __restrict__ h1,
    u16* __restrict__ l1, int nb1, const float* __restrict__ s2,
    u16* __restrict__ h2, u16* __restrict__ l2, int nb2,
    const float* __restrict__ s3, u16* __restrict__ h3, u16* __restrict__ l3) {
  int b = blockIdx.x;
  const float* s;
  u16 *h, *l;
  if (b < nb0) {
    s = s0; h = h0; l = l0;
  } else if (b < nb0 + nb1) {
    b -= nb0; s = s1; h = h1; l = l1;
  } else if (b < nb0 + nb1 + nb2) {
    b -= nb0 + nb1; s = s2; h = h2; l = l2;
  } else {
    b -= nb0 + nb1 + nb2; s = s3; h = h3; l = l3;
  }
  const int i = b * 256 + threadIdx.x;
  const float4 v = ((const float4*)s)[i];
  u16x4 hh, ll;
  hh.x = f2bf_rne(v.x); ll.x = f2bf_rne(v.x - bf2f(hh.x));
  hh.y = f2bf_rne(v.y); ll.y = f2bf_rne(v.y - bf2f(hh.y));
  hh.z = f2bf_rne(v.z); ll.z = f2bf_rne(v.z - bf2f(hh.z));
  hh.w = f2bf_rne(v.w); ll.w = f2bf_rne(v.w - bf2f(hh.w));
  ((u16x4*)h)[i] = hh;
  ((u16x4*)l)[i] = ll;
}

// ---------------- row L2 normalize, optional fp32 + hi/lo + best-init ------
template <int WF32>
__global__ __launch_bounds__(256) void l2norm_ext(const float* __restrict__ in,
                                                  float* __restrict__ outF,
                                                  u16* __restrict__ outH,
                                                  u16* __restrict__ outL,
                                                  float* __restrict__ ssq,
                                                  u64* __restrict__ binit) {
  const int row = blockIdx.x;
  const float4 v = ((const float4*)(in + (size_t)row * C_DIM))[threadIdx.x];
  float ss = v.x * v.x + v.y * v.y + v.z * v.z + v.w * v.w;
  ss = block_reduce_sum_256(ss);
  float nrm = sqrtf(ss);
  nrm = fmaxf(nrm, 1e-12f);
  float4 o;
  o.x = v.x / nrm; o.y = v.y / nrm; o.z = v.z / nrm; o.w = v.w / nrm;
  if (WF32) ((float4*)(outF + (size_t)row * C_DIM))[threadIdx.x] = o;
  u16x4 h, l;
  h.x = f2bf_rne(o.x); l.x = f2bf_rne(o.x - bf2f(h.x));
  h.y = f2bf_rne(o.y); l.y = f2bf_rne(o.y - bf2f(h.y));
  h.z = f2bf_rne(o.z); l.z = f2bf_rne(o.z - bf2f(h.z));
  h.w = f2bf_rne(o.w); l.w = f2bf_rne(o.w - bf2f(h.w));
  ((u16x4*)(outH + (size_t)row * C_DIM))[threadIdx.x] = h;
  ((u16x4*)(outL + (size_t)row * C_DIM))[threadIdx.x] = l;
  float s2 = o.x * o.x + o.y * o.y + o.z * o.z + o.w * o.w;
  s2 = block_reduce_sum_256(s2);
  if (threadIdx.x == 0) {
    ssq[row] = s2;
    if (binit) binit[row] = ~0ull;
  }
}

// ---------------- split-bf16 MFMA NT GEMM ----------------------------------
// C = A@B^T from pre-split hi/lo operands.  Staging: global_load_lds width-16,
// single 32KB buffer, pre-swizzled global source (r10-verified).
// Per-instantiation policy (r15, measured):
//   TB=0 (squares): all-frags-upfront + launch_bounds(256,2) + XCD tile
//       swizzle (r14: -58us combined on squares; weights L2-fit per XCD).
//   TB=1 (dist): term-batched frags + launch_bounds(256,4), NO swizzle
//       (r14 showed swizzle 3x's dist FETCH; r12's default order is optimal).
// Both remaps are bijective tile permutations -> outputs bitwise identical.
// TERMS: 3 = hh+hl+lh, 4 = +ll (near-fp32, encoder).
// MODE:  0 = +bias -> fp32 out. 1 = +bias, tanh -> hi/lo out.
//        2 = distance argmin (bias = |e|^2, uses zz/best).
// CS:    1 = emit per-block column sums of out (cs1=sum, cs2=sum of squares).
template <int MODE, int TERMS, int CS, int TB>
__global__ __launch_bounds__(256, (TB ? 4 : 2)) void gemm_bf3(
    const u16* __restrict__ Ahg, const u16* __restrict__ Alg,
    const u16* __restrict__ Bhg, const u16* __restrict__ Blg,
    const float* __restrict__ bias, float* __restrict__ outF,
    u16* __restrict__ outH, u16* __restrict__ outL, float* __restrict__ cs1,
    float* __restrict__ cs2, const float* __restrict__ zz,
    u64* __restrict__ best, int N) {
  // planes: Ah [0,4096), Al [4096,8192), Bh [8192,12288), Bl [12288,16384)
  __shared__ __align__(16) u16 lds[16384];
  __shared__ float csum[CS ? 4 * 64 * 2 : 1];
  const int tid = threadIdx.x;
  const int lane = tid & 63, w = tid >> 6;
  const int wr = w >> 1, wc = w & 1;

  int bx, by;
  if (TB) {
    bx = blockIdx.x;
    by = blockIdx.y;
  } else {
    // XCD-aware bijective tile remap (grids %8==0): bid' = (bid&7)*(nb/8)+(bid>>3)
    const int gx = gridDim.x;
    const int nb = gx * gridDim.y;
    int bid = blockIdx.y * gx + blockIdx.x;
    bid = (bid & 7) * (nb >> 3) + (bid >> 3);
    bx = bid % gx;
    by = bid / gx;
  }
  const int m0 = by * 128, n0 = bx * 128;

  // staging: wave w covers rows [w*32, w*32+32), 2 issues of 16 rows/array.
  // LDS linear; global source chunk pre-swizzled: c = (lane&3) ^ ((row>>1)&3)
  const int r0l = w * 32 + (lane >> 2);
  const int r1l = r0l + 16;
  const int c0 = (((lane & 3) ^ ((r0l >> 1) & 3)) << 3);
  const int c1 = (((lane & 3) ^ ((r1l >> 1) & 3)) << 3);
  const u16* pAh0 = Ahg + (size_t)(m0 + r0l) * KK + c0;
  const u16* pAh1 = Ahg + (size_t)(m0 + r1l) * KK + c1;
  const u16* pAl0 = Alg + (size_t)(m0 + r0l) * KK + c0;
  const u16* pAl1 = Alg + (size_t)(m0 + r1l) * KK + c1;
  const u16* pBh0 = Bhg + (size_t)(n0 + r0l) * KK + c0;
  const u16* pBh1 = Bhg + (size_t)(n0 + r1l) * KK + c1;
  const u16* pBl0 = Blg + (size_t)(n0 + r0l) * KK + c0;
  const u16* pBl1 = Blg + (size_t)(n0 + r1l) * KK + c1;
  u16* const db = lds + w * 1024;  // wave-uniform LDS dest (32 rows)

  // fragment-read offsets (u16 units) — identical to r6/r10 (0 conflicts)
  int oa[4], ob[4];
  const int q = lane >> 4;
#pragma unroll
  for (int t = 0; t < 4; ++t) {
    const int ra = wr * 64 + t * 16 + (lane & 15);
    oa[t] = ra * 32 + ((q ^ ((ra >> 1) & 3)) << 3);
    const int rb = wc * 64 + t * 16 + (lane & 15);
    ob[t] = rb * 32 + ((q ^ ((rb >> 1) & 3)) << 3);
  }

  f32x4 acc[4][4];
#pragma unroll
  for (int i = 0; i < 4; ++i)
#pragma unroll
    for (int j = 0; j < 4; ++j) acc[i][j] = (f32x4){0.f, 0.f, 0.f, 0.f};

  for (int k0 = 0; k0 < KK; k0 += 32) {
    __syncthreads();  // all waves done reading previous tile
    gl2lds(pAh0 + k0, db);
    gl2lds(pAh1 + k0, db + 512);
    gl2lds(pAl0 + k0, db + 4096);
    gl2lds(pAl1 + k0, db + 4608);
    gl2lds(pBh0 + k0, db + 8192);
    gl2lds(pBh1 + k0, db + 8704);
    gl2lds(pBl0 + k0, db + 12288);
    gl2lds(pBl1 + k0, db + 12800);
    asm volatile("s_waitcnt vmcnt(0)" ::: "memory");
    __syncthreads();  // every wave's tile landed

    if (TB) {
      // term-batched: peak live frags = 12 (48 VGPRs) -> fits 64-VGPR budget
      short8 fa[4], fb[4], fx[4];
#pragma unroll
      for (int t = 0; t < 4; ++t) {
        fa[t] = *(const short8*)(lds + oa[t]);           // ah
        fb[t] = *(const short8*)(lds + 8192 + ob[t]);    // bh
      }
#pragma unroll
      for (int i = 0; i < 4; ++i)
#pragma unroll
        for (int j = 0; j < 4; ++j)
          acc[i][j] = __builtin_amdgcn_mfma_f32_16x16x32_bf16(
              fa[i], fb[j], acc[i][j], 0, 0, 0);
#pragma unroll
      for (int t = 0; t < 4; ++t)
        fx[t] = *(const short8*)(lds + 12288 + ob[t]);   // bl
#pragma unroll
      for (int i = 0; i < 4; ++i)
#pragma unroll
        for (int j = 0; j < 4; ++j)
          acc[i][j] = __builtin_amdgcn_mfma_f32_16x16x32_bf16(
              fa[i], fx[j], acc[i][j], 0, 0, 0);
#pragma unroll
      for (int t = 0; t < 4; ++t)
        fa[t] = *(const short8*)(lds + 4096 + oa[t]);    // al (ah dead)
#pragma unroll
      for (int i = 0; i < 4; ++i)
#pragma unroll
        for (int j = 0; j < 4; ++j)
          acc[i][j] = __builtin_amdgcn_mfma_f32_16x16x32_bf16(
              fa[i], fb[j], acc[i][j], 0, 0, 0);
      if (TERMS == 4) {
#pragma unroll
        for (int i = 0; i < 4; ++i)
#pragma unroll
          for (int j = 0; j < 4; ++j)
            acc[i][j] = __builtin_amdgcn_mfma_f32_16x16x32_bf16(
                fa[i], fx[j], acc[i][j], 0, 0, 0);
      }
    } else {
      // r10 body: all 16 frags upfront, per-acc hh,hl,lh(,ll)
      short8 ah[4], al[4], bh[4], bl[4];
#pragma unroll
      for (int t = 0; t < 4; ++t) {
        ah[t] = *(const short8*)(lds + oa[t]);
        al[t] = *(const short8*)(lds + 4096 + oa[t]);
        bh[t] = *(const short8*)(lds + 8192 + ob[t]);
        bl[t] = *(const short8*)(lds + 12288 + ob[t]);
      }
#pragma unroll
      for (int i = 0; i < 4; ++i)
#pragma unroll
        for (int j = 0; j < 4; ++j) {
          acc[i][j] = __builtin_amdgcn_mfma_f32_16x16x32_bf16(
              ah[i], bh[j], acc[i][j], 0, 0, 0);
          acc[i][j] = __builtin_amdgcn_mfma_f32_16x16x32_bf16(
              ah[i], bl[j], acc[i][j], 0, 0, 0);
          acc[i][j] = __builtin_amdgcn_mfma_f32_16x16x32_bf16(
              al[i], bh[j], acc[i][j], 0, 0, 0);
          if (TERMS == 4)
            acc[i][j] = __builtin_amdgcn_mfma_f32_16x16x32_bf16(
                al[i], bl[j], acc[i][j], 0, 0, 0);
        }
    }
  }

  // C/D layout: col = lane&15, row = (lane>>4)*4 + v   [m89-verified]
  const int rbase = m0 + wr * 64 + (lane >> 4) * 4;
  const int cbase = n0 + wc * 64 + (lane & 15);

  if (MODE == 2) {
    float sev[4];
#pragma unroll
    for (int j = 0; j < 4; ++j) sev[j] = bias[cbase + j * 16];
#pragma unroll
    for (int i = 0; i < 4; ++i)
#pragma unroll
      for (int v = 0; v < 4; ++v) {
        const int row = rbase + i * 16 + v;
        const float zr = zz[row];
        u64 bkey = ~0ull;
#pragma unroll
        for (int j = 0; j < 4; ++j) {
          const float d = (zr + sev[j]) - 2.0f * acc[i][j][v];
          const u32 fb2 = __float_as_uint(d);
          const u32 k32 = (fb2 & 0x80000000u) ? ~fb2 : (fb2 | 0x80000000u);
          const u64 key = ((u64)k32 << 32) | (u32)(cbase + j * 16);
          bkey = (key < bkey) ? key : bkey;
        }
#pragma unroll
        for (int mm = 1; mm < 16; mm <<= 1) {
          const u64 o = shfl_xor_u64(bkey, mm);
          bkey = (o < bkey) ? o : bkey;
        }
        if ((lane & 15) == 0) atomicMin(best + row, bkey);
      }
  } else {
    float bb[4];
#pragma unroll
    for (int j = 0; j < 4; ++j) bb[j] = bias[cbase + j * 16];
    float s[4] = {0.f, 0.f, 0.f, 0.f}, ss[4] = {0.f, 0.f, 0.f, 0.f};
#pragma unroll
    for (int i = 0; i < 4; ++i)
#pragma unroll
      for (int j = 0; j < 4; ++j)
#pragma unroll
        for (int v = 0; v < 4; ++v) {
          const int row = rbase + i * 16 + v;
          const int col = cbase + j * 16;
          float val = acc[i][j][v] + bb[j];
          if (MODE == 1) {
            val = tanhf(val);
            const u16 h = f2bf_rne(val);
            outH[(size_t)row * N + col] = h;
            outL[(size_t)row * N + col] = f2bf_rne(val - bf2f(h));
          } else {
            outF[(size_t)row * N + col] = val;
            if (CS) {
              s[j] += val;
              ss[j] += val * val;
            }
          }
        }
    if (CS) {
#pragma unroll
      for (int j = 0; j < 4; ++j) {
        s[j] += __shfl_xor(s[j], 16, 64);
        s[j] += __shfl_xor(s[j], 32, 64);
        ss[j] += __shfl_xor(ss[j], 16, 64);
        ss[j] += __shfl_xor(ss[j], 32, 64);
      }
      if (lane < 16) {
#pragma unroll
        for (int j = 0; j < 4; ++j) {
          csum[(w * 64 + j * 16 + lane) * 2 + 0] = s[j];
          csum[(w * 64 + j * 16 + lane) * 2 + 1] = ss[j];
        }
      }
      __syncthreads();
      if (tid < 128) {
        const int col = tid;
        const int wcc = col >> 6, idx = col & 63;
        const float S = csum[(wcc * 64 + idx) * 2 + 0] +
                        csum[((2 + wcc) * 64 + idx) * 2 + 0];
        const float SS = csum[(wcc * 64 + idx) * 2 + 1] +
                         csum[((2 + wcc) * 64 + idx) * 2 + 1];
        cs1[(size_t)by * C_DIM + n0 + col] = S;
        cs2[(size_t)by * C_DIM + n0 + col] = SS;
      }
    }
  }
}

// ---------------- BN finalize: fold 64 per-block partials -------------------
__global__ __launch_bounds__(256) void bn_stats2(const float* __restrict__ cs1,
                                                 const float* __restrict__ cs2,
                                                 const float* __restrict__ g,
                                                 float* __restrict__ mean,
                                                 float* __restrict__ scale) {
  const int c = blockIdx.x * 256 + threadIdx.x;
  float s = 0.f, ss = 0.f;
  for (int i = 0; i < 64; ++i) {
    s += cs1[i * C_DIM + c];
    ss += cs2[i * C_DIM + c];
  }
  const float m = s * (1.0f / 8192.0f);
  const float v = ss * (1.0f / 8192.0f) - m * m;  // biased var
  mean[c] = m;
  scale[c] = g[c] / sqrtf(v + BN_EPS_C);
}

// ---------------- BN apply + ReLU -> hi/lo ---------------------------------
__global__ __launch_bounds__(256) void bn_relu_cvt(
    const float* __restrict__ t, const float* __restrict__ mean,
    const float* __restrict__ scale, const float* __restrict__ be,
    u16* __restrict__ outH, u16* __restrict__ outL) {
  const int i = blockIdx.x * 256 + threadIdx.x;
  const int c4 = i & 255;
  const float4 v = ((const float4*)t)[i];
  const float4 m = ((const float4*)mean)[c4];
  const float4 sc = ((const float4*)scale)[c4];
  const float4 b = ((const float4*)be)[c4];
  float4 r;
  r.x = fmaxf((v.x - m.x) * sc.x + b.x, 0.f);
  r.y = fmaxf((v.y - m.y) * sc.y + b.y, 0.f);
  r.z = fmaxf((v.z - m.z) * sc.z + b.z, 0.f);
  r.w = fmaxf((v.w - m.w) * sc.w + b.w, 0.f);
  u16x4 h, l;
  h.x = f2bf_rne(r.x); l.x = f2bf_rne(r.x - bf2f(h.x));
  h.y = f2bf_rne(r.y); l.y = f2bf_rne(r.y - bf2f(h.y));
  h.z = f2bf_rne(r.z); l.z = f2bf_rne(r.z - bf2f(h.z));
  h.w = f2bf_rne(r.w); l.w = f2bf_rne(r.w - bf2f(h.w));
  ((u16x4*)outH)[i] = h;
  ((u16x4*)outL)[i] = l;
}

// ---------------- VQ gather (hi/lo e) -> zq hi/lo + row loss ----------------
__global__ __launch_bounds__(256) void gather_zq_cvt(
    const float* __restrict__ z, const u16* __restrict__ eh,
    const u16* __restrict__ el, const u64* __restrict__ best,
    u16* __restrict__ zqh, u16* __restrict__ zql, float* __restrict__ rowp) {
  const int row = blockIdx.x;
  const u32 idx = (u32)(best[row] & 0xffffffffu);
  const float4 zv = ((const float4*)(z + (size_t)row * C_DIM))[threadIdx.x];
  const u16x4 evh = ((const u16x4*)(eh + (size_t)idx * C_DIM))[threadIdx.x];
  const u16x4 evl = ((const u16x4*)(el + (size_t)idx * C_DIM))[threadIdx.x];
  float4 ev;
  ev.x = bf2f(evh.x) + bf2f(evl.x);
  ev.y = bf2f(evh.y) + bf2f(evl.y);
  ev.z = bf2f(evh.z) + bf2f(evl.z);
  ev.w = bf2f(evh.w) + bf2f(evl.w);
  float4 d, o;
  d.x = ev.x - zv.x; d.y = ev.y - zv.y; d.z = ev.z - zv.z; d.w = ev.w - zv.w;
  o.x = zv.x + d.x; o.y = zv.y + d.y; o.z = zv.z + d.z; o.w = zv.w + d.w;
  u16x4 h, l;
  h.x = f2bf_rne(o.x); l.x = f2bf_rne(o.x - bf2f(h.x));
  h.y = f2bf_rne(o.y); l.y = f2bf_rne(o.y - bf2f(h.y));
  h.z = f2bf_rne(o.z); l.z = f2bf_rne(o.z - bf2f(h.z));
  h.w = f2bf_rne(o.w); l.w = f2bf_rne(o.w - bf2f(h.w));
  ((u16x4*)(zqh + (size_t)row * C_DIM))[threadIdx.x] = h;
  ((u16x4*)(zql + (size_t)row * C_DIM))[threadIdx.x] = l;
  float ss = d.x * d.x + d.y * d.y + d.z * d.z + d.w * d.w;
  ss = block_reduce_sum_256(ss);
  if (threadIdx.x == 0) rowp[row] = ss;
}

__global__ __launch_bounds__(256) void embloss_fin(const float* __restrict__ rowp,
                                                   float* __restrict__ out) {
  float s = 0.f;
  for (int i = threadIdx.x; i < B_ROWS; i += 256) s += rowp[i];
  s = block_reduce_sum_256(s);
  if (threadIdx.x == 0) out[0] = s * (1.0f / (8192.0f * 1024.0f));
}

// ---------------- launch ----------------------------------------------------
extern "C" void kernel_launch(void* const* d_in, const int* in_sizes, int n_in,
                              void* d_out, int out_size, void* d_ws,
                              size_t ws_size, hipStream_t stream) {
  const float* x = (const float*)d_in[0];
  const float* enc_W = (const float*)d_in[1];
  const float* enc_b = (const float*)d_in[2];
  const float* enc_g = (const float*)d_in[3];
  const float* enc_be = (const float*)d_in[4];
  const float* enc_vW1 = (const float*)d_in[5];
  const float* enc_vb1 = (const float*)d_in[6];
  const float* enc_vW2 = (const float*)d_in[7];
  const float* enc_vb2 = (const float*)d_in[8];
  const float* dec_W = (const float*)d_in[9];
  const float* dec_b = (const float*)d_in[10];
  const float* dec_g = (const float*)d_in[11];
  const float* dec_be = (const float*)d_in[12];
  const float* dec_vW1 = (const float*)d_in[13];
  const float* dec_vb1 = (const float*)d_in[14];
  const float* dec_vW2 = (const float*)d_in[15];
  const float* dec_vb2 = (const float*)d_in[16];
  const float* cb = (const float*)d_in[17];

  const size_t NE = (size_t)B_ROWS * C_DIM;  // 8388608
  const size_t WN = (size_t)C_DIM * C_DIM;   // 1048576
  float* ws = (float*)d_ws;
  // Four NE-float regions, time-shared by liveness (~128.8 MB total):
  float* R1 = ws;        // h fp32 (enc+dec) | z fp32
  float* R2 = R1 + NE;   // x hi/lo | acts ping | zhi/zlo
  float* R3 = R2 + NE;   // acts pong | enc tanh | zq hi/lo
  float* R4 = R3 + NE;   // enc weight arena -> ehi/elo -> dec weight arena
  float* se = R4 + NE;
  float* zz = se + N_EMB;
  u64* best = (u64*)(zz + B_ROWS);
  float* cs1 = (float*)(best + B_ROWS);  // 64*1024
  float* cs2 = cs1 + 64 * C_DIM;         // 64*1024
  float* mean = cs2 + 64 * C_DIM;
  float* scal = mean + C_DIM;
  float* rowp = scal + C_DIM;

  u16* wa = (u16*)R4;
  u16* ehi = (u16*)R4;   // after encoder: codebook hi/lo replace weights
  u16* elo = ehi + NE;
  u16* xh = (u16*)R2;    // x split
  u16* xl = xh + NE;
  u16* aH = (u16*)R2;    // act ping (same region as x: ping-pong below)
  u16* aL = aH + NE;
  u16* bH = (u16*)R3;    // act pong / tanh / zq
  u16* bL = bH + NE;
  u16* zhi = (u16*)R2;   // z hi/lo (acts dead by then)
  u16* zlo = zhi + NE;
  float* zf = R1;        // z fp32 (in-place l2norm of vW2 output)

  float* xrec = (float*)d_out;
  float* loss = xrec + NE;

  const dim3 blk(256);
  const dim3 gemmGrid(C_DIM / 128, B_ROWS / 128);  // (8, 64)
  const dim3 distGrid(N_EMB / 128, B_ROWS / 128);  // (64, 64)
  const dim3 s2Grid(C_DIM / 256);
  const dim3 brGrid(B_ROWS * C_DIM / 1024);

  // ---- one batched split: enc_W(4WN) + vW1 + vW2 + x ----
  cvt4<<<dim3(4096 + 1024 + 1024 + 8192), blk, 0, stream>>>(
      enc_W, wa, wa + 4 * WN, 4096, enc_vW1, wa + 8 * WN, wa + 9 * WN, 1024,
      enc_vW2, wa + 10 * WN, wa + 11 * WN, 1024, x, xh, xl);

  // ---- encoder: 4 x (GEMM+colsum -> stats2 -> bn_relu_cvt) ----
  gemm_bf3<0, 4, 1, 0><<<gemmGrid, blk, 0, stream>>>(
      xh, xl, wa, wa + 4 * WN, enc_b, R1, nullptr, nullptr, cs1, cs2, nullptr,
      nullptr, C_DIM);
  bn_stats2<<<s2Grid, blk, 0, stream>>>(cs1, cs2, enc_g, mean, scal);
  bn_relu_cvt<<<brGrid, blk, 0, stream>>>(R1, mean, scal, enc_be, bH, bL);

  gemm_bf3<0, 4, 1, 0><<<gemmGrid, blk, 0, stream>>>(
      bH, bL, wa + WN, wa + 5 * WN, enc_b + C_DIM, R1, nullptr, nullptr, cs1,
      cs2, nullptr, nullptr, C_DIM);
  bn_stats2<<<s2Grid, blk, 0, stream>>>(cs1, cs2, enc_g + C_DIM, mean, scal);
  bn_relu_cvt<<<brGrid, blk, 0, stream>>>(R1, mean, scal, enc_be + C_DIM, aH,
                                          aL);

  gemm_bf3<0, 4, 1, 0><<<gemmGrid, blk, 0, stream>>>(
      aH, aL, wa + 2 * WN, wa + 6 * WN, enc_b + 2 * C_DIM, R1, nullptr,
      nullptr, cs1, cs2, nullptr, nullptr, C_DIM);
  bn_stats2<<<s2Grid, blk, 0, stream>>>(cs1, cs2, enc_g + 2 * C_DIM, mean,
                                        scal);
  bn_relu_cvt<<<brGrid, blk, 0, stream>>>(R1, mean, scal, enc_be + 2 * C_DIM,
                                          bH, bL);

  gemm_bf3<0, 4, 1, 0><<<gemmGrid, blk, 0, stream>>>(
      bH, bL, wa + 3 * WN, wa + 7 * WN, enc_b + 3 * C_DIM, R1, nullptr,
      nullptr, cs1, cs2, nullptr, nullptr, C_DIM);
  bn_stats2<<<s2Grid, blk, 0, stream>>>(cs1, cs2, enc_g + 3 * C_DIM, mean,
                                        scal);
  bn_relu_cvt<<<brGrid, blk, 0, stream>>>(R1, mean, scal, enc_be + 3 * C_DIM,
                                          aH, aL);

  // enc VQ head: tanh -> bH/bL, then vW2 -> z fp32 (R1)
  gemm_bf3<1, 4, 0, 0><<<gemmGrid, blk, 0, stream>>>(
      aH, aL, wa + 8 * WN, wa + 9 * WN, enc_vb1, nullptr, bH, bL, nullptr,
      nullptr, nullptr, nullptr, C_DIM);
  gemm_bf3<0, 4, 0, 0><<<gemmGrid, blk, 0, stream>>>(
      bH, bL, wa + 10 * WN, wa + 11 * WN, enc_vb2, zf, nullptr, nullptr,
      nullptr, nullptr, nullptr, nullptr, C_DIM);

  // ---- quantizer ----  (enc weights dead -> R4 becomes codebook hi/lo)
  l2norm_ext<0><<<N_EMB, blk, 0, stream>>>(cb, nullptr, ehi, elo, se, nullptr);
  l2norm_ext<1><<<B_ROWS, blk, 0, stream>>>(zf, zf, zhi, zlo, zz, best);
  gemm_bf3<2, 3, 0, 1><<<distGrid, blk, 0, stream>>>(
      zhi, zlo, ehi, elo, se, nullptr, nullptr, nullptr, nullptr, nullptr, zz,
      best, N_EMB);
  gather_zq_cvt<<<B_ROWS, blk, 0, stream>>>(zf, ehi, elo, best, bH, bL, rowp);
  embloss_fin<<<1, blk, 0, stream>>>(rowp, loss);

  // ---- decoder ----  (ehi/elo dead -> R4 becomes decoder weight arena)
  cvt4<<<dim3(4096 + 1024 + 1024), blk, 0, stream>>>(
      dec_W, wa, wa + 4 * WN, 4096, dec_vW1, wa + 8 * WN, wa + 9 * WN, 1024,
      dec_vW2, wa + 10 * WN, wa + 11 * WN, 1024, nullptr, nullptr, nullptr);

  gemm_bf3<0, 3, 1, 0><<<gemmGrid, blk, 0, stream>>>(
      bH, bL, wa, wa + 4 * WN, dec_b, R1, nullptr, nullptr, cs1, cs2, nullptr,
      nullptr, C_DIM);
  bn_stats2<<<s2Grid, blk, 0, stream>>>(cs1, cs2, dec_g, mean, scal);
  bn_relu_cvt<<<brGrid, blk, 0, stream>>>(R1, mean, scal, dec_be, aH, aL);

  gemm_bf3<0, 3, 1, 0><<<gemmGrid, blk, 0, stream>>>(
      aH, aL, wa + WN, wa + 5 * WN, dec_b + C_DIM, R1, nullptr, nullptr, cs1,
      cs2, nullptr, nullptr, C_DIM);
  bn_stats2<<<s2Grid, blk, 0, stream>>>(cs1, cs2, dec_g + C_DIM, mean, scal);
  bn_relu_cvt<<<brGrid, blk, 0, stream>>>(R1, mean, scal, dec_be + C_DIM, bH,
                                          bL);

  gemm_bf3<0, 3, 1, 0><<<gemmGrid, blk, 0, stream>>>(
      bH, bL, wa + 2 * WN, wa + 6 * WN, dec_b + 2 * C_DIM, R1, nullptr,
      nullptr, cs1, cs2, nullptr, nullptr, C_DIM);
  bn_stats2<<<s2Grid, blk, 0, stream>>>(cs1, cs2, dec_g + 2 * C_DIM, mean,
                                        scal);
  bn_relu_cvt<<<brGrid, blk, 0, stream>>>(R1, mean, scal, dec_be + 2 * C_DIM,
                                          aH, aL);

  gemm_bf3<0, 3, 1, 0><<<gemmGrid, blk, 0, stream>>>(
      aH, aL, wa + 3 * WN, wa + 7 * WN, dec_b + 3 * C_DIM, R1, nullptr,
      nullptr, cs1, cs2, nullptr, nullptr, C_DIM);
  bn_stats2<<<s2Grid, blk, 0, stream>>>(cs1, cs2, dec_g + 3 * C_DIM, mean,
                                        scal);
  bn_relu_cvt<<<brGrid, blk, 0, stream>>>(R1, mean, scal, dec_be + 3 * C_DIM,
                                          bH, bL);

  // dec VQ head -> xrec
  gemm_bf3<1, 3, 0, 0><<<gemmGrid, blk, 0, stream>>>(
      bH, bL, wa + 8 * WN, wa + 9 * WN, dec_vb1, nullptr, aH, aL, nullptr,
      nullptr, nullptr, nullptr, C_DIM);
  gemm_bf3<0, 3, 0, 0><<<gemmGrid, blk, 0, stream>>>(
      aH, aL, wa + 10 * WN, wa + 11 * WN, dec_vb2, xrec, nullptr, nullptr,
      nullptr, nullptr, nullptr, nullptr, C_DIM);
}